// Round 3
// baseline (142.429 us; speedup 1.0000x reference)
//
#include <hip/hip_runtime.h>
#include <math.h>
#include <complex>

// SO3 irrep rotation: out = Dy(alpha) J Dy(beta) J Dy(gamma) x, per irrep l=0..8, mul=64.
// R10 = R9 (compose-once per row-wave, no block barriers, TLP overlap) with the compose
// phase's LDS traffic restructured for b128 access. Math is bit-identical to R9
// (harness-verified, absmax 0.0156); only LDS layouts changed:
//   - J staged into LDS with 16B-padded row pitch rp(l): stage-B J reads become
//     ds_read_b128 row chunks (was per-element b32).
//   - compose scratch stored TRANSPOSED (PwT[j][k], pitch rp): stage-B's k-loop reads
//     PwT row j as b128 chunks (was stride-d b32 gather).
//   Per element stage B now issues 3*ceil(d/4) b128 instead of 3d b32 -> compose LDS
//   ops drop ~3.5x (~460 -> ~140 wave-ops/row). Tail chunks use compile-time component
//   guards (pad bytes read, never accumulated) -> no zero-fill, no extra fences.
// Apply (broadcast b128 matvec), early x-load burst, NT stores, per-wave lgkmcnt
// fences (rule #18), LDS 24.4 KB -> 6 blocks/CU: all unchanged from R9.

#define LMAX 8
#define BATCH 16384
#define DIM 5184
#define NJ 969   // sum (2l+1)^2  (unpadded J, as passed through d_ws)
#define NP 1140  // padded size: sum (2l+1)*rp(l)  (used for both sJ and sD)

__host__ __device__ constexpr int d_of(int l) { return 2 * l + 1; }
__host__ __device__ constexpr int joff_u(int l) {
    int o = 0;
    for (int k = 0; k < l; ++k) o += d_of(k) * d_of(k);
    return o;
}
__host__ __device__ constexpr int rp_of(int l) { return (d_of(l) + 3) & ~3; }  // row pitch, mult of 4
__host__ __device__ constexpr int poff_u(int l) {   // padded block offset (floats), 16B-aligned
    int o = 0;
    for (int k = 0; k < l; ++k) o += d_of(k) * rp_of(k);
    return o;
}
// poff: 0,4,16,56,112,220,352,560,800 ; NP=1140.
// Compose scratch aliasing (per wave, within sD[wave]):
//   L=8: PwT = Dw+0   (needs 17*20=340 < 352 = start of D[6]; D[8] lives at [800,1140))
//   L<8: PwT = Dw+800 (dead D[8] region, needs d*rp <= 240; D[l<8] all end < 800)

struct JPack { float v[NJ]; };

// ---------------- host-side J computation (validated R1-R9, unchanged) ----------------
static void compute_J_host(JPack* jp) {
    for (int l = 0; l <= LMAX; ++l) {
        const int d = 2 * l + 1;
        std::complex<double> q[289], Ac[289], T1[289];
        double A[289], E[289], Tm[289], P[289];
        const double is2 = 1.0 / std::sqrt(2.0);
        static const double pr[4] = {1.0, 0.0, -1.0, 0.0};
        static const double pim[4] = {0.0, -1.0, 0.0, 1.0};
        const int ph = l & 3;
        for (int i = 0; i < d; ++i) {
            for (int j = 0; j < d; ++j) {
                double re = 0.0, im = 0.0;
                const int mm = i - l;
                if (mm < 0) {
                    if (j == l - mm) re = is2;
                    if (j == l + mm) im = -is2;
                } else if (mm == 0) {
                    if (j == l) re = 1.0;
                } else {
                    const double sgn = (mm & 1) ? -1.0 : 1.0;
                    if (j == l + mm) re = sgn * is2;
                    if (j == l - mm) im = sgn * is2;
                }
                q[i * d + j] = std::complex<double>(re * pr[ph] - im * pim[ph],
                                                    re * pim[ph] + im * pr[ph]);
                double xr = 0.0;
                if (j == i - 1) {
                    const double m = (double)(i - 1 - l);
                    xr += -0.5 * std::sqrt((double)l * (l + 1) - m * (m + 1));
                }
                if (j == i + 1) {
                    const double m = (double)(i - l + 1);
                    xr += 0.5 * std::sqrt((double)l * (l + 1) - m * (m - 1));
                }
                Ac[i * d + j] = std::complex<double>(xr, (i == j) ? (double)(i - l) : 0.0);
            }
        }
        for (int i = 0; i < d; ++i)
            for (int j = 0; j < d; ++j) {
                std::complex<double> s = 0.0;
                for (int k = 0; k < d; ++k) s += Ac[i * d + k] * q[k * d + j];
                T1[i * d + j] = s;
            }
        for (int i = 0; i < d; ++i)
            for (int j = 0; j < d; ++j) {
                std::complex<double> s = 0.0;
                for (int k = 0; k < d; ++k) s += std::conj(q[k * d + i]) * T1[k * d + j];
                A[i * d + j] = s.real() * (M_PI / std::sqrt(2.0));
            }
        double mx = 0.0;
        for (int i = 0; i < d; ++i) {
            double s = 0.0;
            for (int k = 0; k < d; ++k) s += std::fabs(A[i * d + k]);
            mx = std::fmax(mx, s);
        }
        int sh = 0;
        while (mx > 0.25 && sh < 60) { mx *= 0.5; ++sh; }
        const double sc = std::ldexp(1.0, -sh);
        for (int t = 0; t < d * d; ++t) A[t] *= sc;
        for (int i = 0; i < d; ++i)
            for (int j = 0; j < d; ++j) E[i * d + j] = Tm[i * d + j] = (i == j) ? 1.0 : 0.0;
        for (int kk = 1; kk <= 16; ++kk) {
            for (int i = 0; i < d; ++i)
                for (int j = 0; j < d; ++j) {
                    double s = 0.0;
                    for (int k = 0; k < d; ++k) s += Tm[i * d + k] * A[k * d + j];
                    P[i * d + j] = s / (double)kk;
                }
            for (int t = 0; t < d * d; ++t) { Tm[t] = P[t]; E[t] += P[t]; }
        }
        for (int q2 = 0; q2 < sh; ++q2) {
            for (int i = 0; i < d; ++i)
                for (int j = 0; j < d; ++j) {
                    double s = 0.0;
                    for (int k = 0; k < d; ++k) s += E[i * d + k] * E[k * d + j];
                    P[i * d + j] = s;
                }
            for (int t = 0; t < d * d; ++t) E[t] = P[t];
        }
        for (int i = 0; i < d; ++i)
            for (int j = 0; j < d; ++j)
                jp->v[joff_u(l) + i * d + j] = (float)E[i * d + j];
    }
}

// per-wave LDS RAW fence: drain this wave's outstanding LDS ops, pin program order.
__device__ __forceinline__ void wave_lds_fence() {
    asm volatile("s_waitcnt lgkmcnt(0)" ::: "memory");
    __builtin_amdgcn_sched_barrier(0);
}

// stage Jg (unpadded, global) -> sJ (row-padded, LDS), block-cooperative
template <int L>
__device__ __forceinline__ void stage_J(float* __restrict__ sJ, const float* __restrict__ Jg,
                                        int tid) {
    constexpr int d = d_of(L), RP = rp_of(L);
    const float* src = Jg + joff_u(L);
    float* dst = sJ + poff_u(L);
    for (int t = tid; t < d * d; t += 256) {
        const int i = t / d, j = t - i * d;   // d constexpr -> magic-mul
        dst[i * RP + j] = src[t];
    }
}

// ---------------- per-l block: load burst -> compose (2 stages) -> matvec -> store ----
// Dy(theta)[i,j] = delta_{j,i} cos((l-i)th) + delta_{j,d-1-i} sin((l-i)th)
// T[a][0][m+8] = cos(m*th_a), T[a][1][m+8] = sin(m*th_a); a: 0=gamma,1=beta,2=alpha.
// Values identical to R9 (harness-verified); only LDS placement changed (padded J,
// transposed Pw).
template <int L, int PWOFF>
__device__ __forceinline__ void process(const float* __restrict__ xb,
                                        float* __restrict__ ob,
                                        const float* __restrict__ sJ,
                                        float* Dw,
                                        const float (&T)[3][2][17],
                                        int lane) {
    constexpr int d = d_of(L), h = (d + 1) / 2, RP = rp_of(L);
    const float* J = sJ + poff_u(L);           // padded rows, pitch RP
    float* D = Dw + poff_u(L);
    float* Pw = Dw + PWOFF;                    // TRANSPOSED scratch: PwT[j*RP + k]
    const float* p = xb + 64 * L * L;
    float* o = ob + 64 * L * L;

    // issue x loads first: latency hides under compose
    float A[d];
#pragma unroll
    for (int i = 0; i < d; ++i) A[i] = p[i * 64];

    // stage A: PwT[j][i] = (Dy(beta) * (J * Dy(gamma)))[i][j], rows paired (i, d-1-i)
    for (int t = lane; t < h * d; t += 64) {
        const int i = t / d, j = t - i * d;
        const int i2 = d - 1 - i, j2 = d - 1 - j;
        const float cg = T[0][0][(L - j) + 8], sg = T[0][1][(L - j) + 8];
        const float p1a = J[i * RP + j] * cg - J[i * RP + j2] * sg;
        const float p1b = J[i2 * RP + j] * cg - J[i2 * RP + j2] * sg;
        const float cb = T[1][0][(L - i) + 8], sb = T[1][1][(L - i) + 8];
        Pw[j * RP + i]  = cb * p1a + sb * p1b;
        Pw[j * RP + i2] = cb * p1b - sb * p1a;
    }
    wave_lds_fence();

    // stage B: D = Dy(alpha) * (J * P); all three operands read as b128 row chunks.
    for (int t = lane; t < h * d; t += 64) {
        const int i = t / d, j = t - i * d;
        const int i2 = d - 1 - i;
        const float4* Ji  = reinterpret_cast<const float4*>(J + i * RP);
        const float4* Ji2 = reinterpret_cast<const float4*>(J + i2 * RP);
        const float4* Pj  = reinterpret_cast<const float4*>(Pw + j * RP);
        float ta = 0.f, tb = 0.f;
#pragma unroll
        for (int q = 0; q < RP / 4; ++q) {
            const float4 pv = Pj[q], ja = Ji[q], jb = Ji2[q];
            if (4 * q + 0 < d) { ta += ja.x * pv.x; tb += jb.x * pv.x; }
            if (4 * q + 1 < d) { ta += ja.y * pv.y; tb += jb.y * pv.y; }
            if (4 * q + 2 < d) { ta += ja.z * pv.z; tb += jb.z * pv.z; }
            if (4 * q + 3 < d) { ta += ja.w * pv.w; tb += jb.w * pv.w; }
        }
        const float ca = T[2][0][(L - i) + 8], sa = T[2][1][(L - i) + 8];
        D[i * RP + j]  = ca * ta + sa * tb;
        D[i2 * RP + j] = ca * tb - sa * ta;
    }
    wave_lds_fence();

    // apply: out = D * x, D broadcast from LDS (uniform addr, conflict-free b128)
#pragma unroll
    for (int i = 0; i < d; ++i) {
        const float4* row = reinterpret_cast<const float4*>(D + i * RP);  // 16B aligned
        float acc = 0.f;
#pragma unroll
        for (int q = 0; q < RP / 4; ++q) {
            const float4 f = row[q];
            if (4 * q + 0 < d) acc += f.x * A[4 * q + 0];
            if (4 * q + 1 < d) acc += f.y * A[4 * q + 1];
            if (4 * q + 2 < d) acc += f.z * A[4 * q + 2];
            if (4 * q + 3 < d) acc += f.w * A[4 * q + 3];
        }
        __builtin_nontemporal_store(acc, o + i * 64);
    }
}

__global__ __launch_bounds__(256) void rot_main(const float* __restrict__ gamma,
                                                const float* __restrict__ beta,
                                                const float* __restrict__ alpha,
                                                const float* __restrict__ x,
                                                float* __restrict__ out,
                                                const float* __restrict__ Jg) {
    __shared__ __align__(16) float sJ[NP];       // J, row-padded to 16B pitch
    __shared__ __align__(16) float sD[4][NP];    // composed D per wave; also compose scratch
    __shared__ float sT[4][3][2][17];            // trig tables per wave
    // LDS: 4560 + 18240 + 1632 = 24432 B -> 6 blocks/CU (24 waves/CU)

    const int tid = threadIdx.x;
    const int wave = tid >> 6, lane = tid & 63;
    const int b = blockIdx.x * 4 + wave;   // one batch row per wave

    stage_J<0>(sJ, Jg, tid);
    stage_J<1>(sJ, Jg, tid);
    stage_J<2>(sJ, Jg, tid);
    stage_J<3>(sJ, Jg, tid);
    stage_J<4>(sJ, Jg, tid);
    stage_J<5>(sJ, Jg, tid);
    stage_J<6>(sJ, Jg, tid);
    stage_J<7>(sJ, Jg, tid);
    stage_J<8>(sJ, Jg, tid);

    if (lane < 51) {   // 3 angles x 17 harmonics: cos/sin(m*theta), m in [-8,8]
        const int a = lane / 17, mm = lane - a * 17;
        const float th = (a == 0) ? gamma[b] : ((a == 1) ? beta[b] : alpha[b]);
        float s, c;
        __sincosf((float)(mm - 8) * th, &s, &c);
        sT[wave][a][0][mm] = c;
        sT[wave][a][1][mm] = s;
    }
    __syncthreads();   // the ONLY block barrier: sJ (block-coop) + sT visible

    const float (&T)[3][2][17] = sT[wave];
    float* Dw = sD[wave];

    const float* xb = x + (size_t)b * DIM + lane;
    float* ob = out + (size_t)b * DIM + lane;

    // l=8 first: compose scratch aliases the not-yet-written D[0..5] region [0,352).
    // l=7..0: scratch aliases the dead D[8] region [800,1140).
    process<8, 0>(xb, ob, sJ, Dw, T, lane);
    process<7, 800>(xb, ob, sJ, Dw, T, lane);
    process<6, 800>(xb, ob, sJ, Dw, T, lane);
    process<5, 800>(xb, ob, sJ, Dw, T, lane);
    process<4, 800>(xb, ob, sJ, Dw, T, lane);
    process<3, 800>(xb, ob, sJ, Dw, T, lane);
    process<2, 800>(xb, ob, sJ, Dw, T, lane);
    process<1, 800>(xb, ob, sJ, Dw, T, lane);
    process<0, 800>(xb, ob, sJ, Dw, T, lane);
}

extern "C" void kernel_launch(void* const* d_in, const int* in_sizes, int n_in,
                              void* d_out, int out_size, void* d_ws, size_t ws_size,
                              hipStream_t stream) {
    const float* gamma = (const float*)d_in[0];
    const float* beta  = (const float*)d_in[1];
    const float* alpha = (const float*)d_in[2];
    const float* x     = (const float*)d_in[3];
    float* out = (float*)d_out;

    static JPack jp;
    static bool init = false;
    if (!init) { compute_J_host(&jp); init = true; }   // deterministic, pure host math

    // J -> workspace (3876 B); graph-capture-safe async copy, static host source.
    hipMemcpyAsync(d_ws, jp.v, sizeof(JPack), hipMemcpyHostToDevice, stream);

    hipLaunchKernelGGL(rot_main, dim3(BATCH / 4), dim3(256), 0, stream,
                       gamma, beta, alpha, x, out, (const float*)d_ws);
}